// Round 4
// baseline (219.895 us; speedup 1.0000x reference)
//
#include <hip/hip_runtime.h>

#define GRID_N 112
#define O_MAX 48
#define HW_N (GRID_N * GRID_N)   // 12544
#define NT 256
#define KPAD 64                  // K padded to 64 (2 MFMA K-steps of 32)
#define LSTR 72                  // table row stride in f16 (144 B; measured conflict cost ~0)

typedef _Float16 half8  __attribute__((ext_vector_type(8)));
typedef _Float16 half4v __attribute__((ext_vector_type(4)));
typedef _Float16 half2v __attribute__((ext_vector_type(2)));
typedef float    f32x4  __attribute__((ext_vector_type(4)));

// Phase 1: signed f16 gaussian tables [pos][k], K zero-padded to 64.
// Phase 2: MFMA 49 16x16 tiles -> cmap[h][w] = 0.5 + sum_k A*B  (f16 in LDS).
// Phase 3: pure coalesced stream: out = mask ? cmap : 0.
__global__ __launch_bounds__(NT, 2) void goalmap_kernel(
    const float* __restrict__ xL, const float* __restrict__ yL,
    const float* __restrict__ obj_list, const int* __restrict__ obj_num,
    const int* __restrict__ road_mask, float* __restrict__ out)
{
    constexpr float INV = 1.0f / (2.0f * 5.0f * 5.0f);  // SIGMA = 5.0

    __shared__ _Float16 exT[GRID_N * LSTR];   // 16128 B
    __shared__ _Float16 eyT[GRID_N * LSTR];   // 16128 B
    __shared__ _Float16 cmap[HW_N];           // 25088 B  (total 57344 B -> 2 blocks/CU)

    const int b   = blockIdx.x;
    const int tid = threadIdx.x;
    const int n   = obj_num[b];               // in [0, 48]
    const float xl = xL[b];
    const float yl = yL[b];
    const float* ob = obj_list + (size_t)b * O_MAX * 2;

    // --- Phase 1: tables ---
    for (int i = tid; i < GRID_N * (KPAD / 2); i += NT) {
        int pos = i >> 5;
        int o0  = (i & 31) * 2;
        half2v vx, vy;
        #pragma unroll
        for (int j = 0; j < 2; ++j) {
            int o = o0 + j;
            float valx = 0.f, valy = 0.f;
            if (o <= n) {
                float cx, cy, s;
                if (o < n) { cx = ob[o * 2 + 1]; cy = ob[o * 2 + 0]; s = -0.5f; }
                else       { cx = xl;            cy = yl;            s =  0.5f; }
                float dx = (float)pos - cx;
                float dy = (float)pos - cy;
                valx = s * __expf(-dx * dx * INV);
                valy =     __expf(-dy * dy * INV);
            }
            vx[j] = (_Float16)valx;
            vy[j] = (_Float16)valy;
        }
        *(half2v*)&exT[pos * LSTR + o0] = vx;
        *(half2v*)&eyT[pos * LSTR + o0] = vy;
    }
    __syncthreads();

    // --- Phase 2: MFMA -> cmap (LDS) ---
    const int lane = tid & 63;
    const int wid  = tid >> 6;      // 4 waves
    const int m    = lane & 15;
    const int quad = lane >> 4;

    for (int t = wid; t < 49; t += 4) {
        int th = t / 7;
        int tw = t - th * 7;

        const _Float16* arow = &exT[(th * 16 + m) * LSTR + quad * 8];
        const _Float16* brow = &eyT[(tw * 16 + m) * LSTR + quad * 8];
        half8 a0 = *(const half8*)arow;
        half8 b0 = *(const half8*)brow;
        half8 a1 = *(const half8*)(arow + 32);
        half8 b1 = *(const half8*)(brow + 32);

        f32x4 acc = {0.f, 0.f, 0.f, 0.f};
        acc = __builtin_amdgcn_mfma_f32_16x16x32_f16(a0, b0, acc, 0, 0, 0);
        acc = __builtin_amdgcn_mfma_f32_16x16x32_f16(a1, b1, acc, 0, 0, 0);

        int h0 = th * 16 + quad * 4;   // C/D: row = quad*4 + reg
        int w0 = tw * 16 + m;          //      col = lane&15
        #pragma unroll
        for (int r = 0; r < 4; ++r)
            cmap[(h0 + r) * GRID_N + w0] = (_Float16)(0.5f + acc[r]);
    }
    __syncthreads();

    // --- Phase 3: pure coalesced streaming ---
    const int4*  rm4 = (const int4*)(road_mask + (size_t)b * HW_N);
    float4*      op4 = (float4*)(out + (size_t)b * HW_N);

    // 3136 float4s total = 12*256 + 64
    #pragma unroll
    for (int it = 0; it < 3; ++it) {
        int4   mv[4];
        half4v cv[4];
        #pragma unroll
        for (int j = 0; j < 4; ++j) mv[j] = rm4[(it * 4 + j) * NT + tid];
        #pragma unroll
        for (int j = 0; j < 4; ++j)
            cv[j] = *(const half4v*)&cmap[((it * 4 + j) * NT + tid) * 4];
        #pragma unroll
        for (int j = 0; j < 4; ++j) {
            float4 v;
            v.x = (mv[j].x == 0) ? 0.f : (float)cv[j][0];
            v.y = (mv[j].y == 0) ? 0.f : (float)cv[j][1];
            v.z = (mv[j].z == 0) ? 0.f : (float)cv[j][2];
            v.w = (mv[j].w == 0) ? 0.f : (float)cv[j][3];
            op4[(it * 4 + j) * NT + tid] = v;
        }
    }
    if (tid < 64) {
        int idx = 12 * NT + tid;   // 3072..3135
        int4   mv = rm4[idx];
        half4v cv = *(const half4v*)&cmap[idx * 4];
        float4 v;
        v.x = (mv.x == 0) ? 0.f : (float)cv[0];
        v.y = (mv.y == 0) ? 0.f : (float)cv[1];
        v.z = (mv.z == 0) ? 0.f : (float)cv[2];
        v.w = (mv.w == 0) ? 0.f : (float)cv[3];
        op4[idx] = v;
    }
}

extern "C" void kernel_launch(void* const* d_in, const int* in_sizes, int n_in,
                              void* d_out, int out_size, void* d_ws, size_t ws_size,
                              hipStream_t stream) {
    const float* xL        = (const float*)d_in[0];
    const float* yL        = (const float*)d_in[1];
    const float* obj_list  = (const float*)d_in[2];
    const int*   obj_num   = (const int*)d_in[3];
    const int*   road_mask = (const int*)d_in[4];
    float*       out       = (float*)d_out;
    const int B = in_sizes[0];  // 2048

    goalmap_kernel<<<B, NT, 0, stream>>>(xL, yL, obj_list, obj_num, road_mask, out);
}

// Round 5
// 207.217 us; speedup vs baseline: 1.0612x; 1.0612x over previous
//
#include <hip/hip_runtime.h>

#define GRID_N 112
#define O_MAX 48
#define HW_N (GRID_N * GRID_N)   // 12544
#define NT 256
#define KPAD 64                  // K padded to 64 (2 MFMA K-steps of 32)
#define LSTR 72                  // table row stride in f16 (144 B, 16B-aligned rows)

typedef _Float16 half8  __attribute__((ext_vector_type(8)));
typedef _Float16 half2v __attribute__((ext_vector_type(2)));
typedef float    f32x4  __attribute__((ext_vector_type(4)));

// channel[b,h,w] = 0.5 + sum_k A[h,k]*B[w,k], masked by road_mask.
// A rows carry sign/scale: k<n -> -0.5*obj gauss, k==n -> +0.5*goal gauss, k>n -> 0.
__global__ __launch_bounds__(NT) void goalmap_kernel(
    const float* __restrict__ xL, const float* __restrict__ yL,
    const float* __restrict__ obj_list, const int* __restrict__ obj_num,
    const int* __restrict__ road_mask, float* __restrict__ out)
{
    constexpr float INV = 1.0f / (2.0f * 5.0f * 5.0f);  // SIGMA = 5.0

    __shared__ float    obj_s[O_MAX * 2];       // 384 B
    __shared__ _Float16 exT[GRID_N * LSTR];     // 16128 B  [h][k]
    __shared__ _Float16 eyT[GRID_N * LSTR];     // 16128 B  [w][k]

    const int b   = blockIdx.x;
    const int tid = threadIdx.x;
    const int n   = obj_num[b];                 // uniform -> s_load
    const float xl = xL[b];
    const float yl = yL[b];
    const float* ob = obj_list + (size_t)b * O_MAX * 2;

    // (1) stage obj coords into LDS (first into the vmcnt queue, tiny)
    if (tid < O_MAX * 2) obj_s[tid] = ob[tid];

    const int lane = tid & 63;
    const int wid  = tid >> 6;                  // 4 waves
    const int m    = lane & 15;
    const int quad = lane >> 4;

    const int* rm = road_mask + (size_t)b * HW_N;
    float*     op = out       + (size_t)b * HW_N;

    // (2) prefetch ALL mask dwords this wave needs, in MFMA C/D layout.
    //     52 outstanding loads/lane = 13.3 KB/wave in flight at once.
    int mpf[13][4];
    #pragma unroll
    for (int i = 0; i < 13; ++i) {
        int t = wid + i * 4;                    // wave-uniform guard
        if (t < 49) {
            int th = t / 7, tw = t - th * 7;
            int base = (th * 16 + quad * 4) * GRID_N + tw * 16 + m;
            #pragma unroll
            for (int r = 0; r < 4; ++r)
                mpf[i][r] = rm[base + r * GRID_N];
        }
    }

    __syncthreads();   // obj_s visible

    // (3) build signed f16 tables [pos][k], K zero-padded to 64
    for (int i = tid; i < GRID_N * (KPAD / 2); i += NT) {
        int pos = i >> 5;
        int o0  = (i & 31) * 2;
        half2v vx, vy;
        #pragma unroll
        for (int j = 0; j < 2; ++j) {
            int o = o0 + j;
            float valx = 0.f, valy = 0.f;
            if (o <= n) {
                float cx, cy, s;
                if (o < n) { cx = obj_s[o * 2 + 1]; cy = obj_s[o * 2 + 0]; s = -0.5f; }
                else       { cx = xl;               cy = yl;               s =  0.5f; }
                float dx = (float)pos - cx;
                float dy = (float)pos - cy;
                valx = s * __expf(-dx * dx * INV);
                valy =     __expf(-dy * dy * INV);
            }
            vx[j] = (_Float16)valx;
            vy[j] = (_Float16)valy;
        }
        *(half2v*)&exT[pos * LSTR + o0] = vx;
        *(half2v*)&eyT[pos * LSTR + o0] = vy;
    }
    __syncthreads();

    // (4) MFMA tiles; combine with prefetched masks; nontemporal stores
    #pragma unroll
    for (int i = 0; i < 13; ++i) {
        int t = wid + i * 4;
        if (t < 49) {
            int th = t / 7, tw = t - th * 7;
            const _Float16* arow = &exT[(th * 16 + m) * LSTR + quad * 8];
            const _Float16* brow = &eyT[(tw * 16 + m) * LSTR + quad * 8];
            half8 a0 = *(const half8*)arow;
            half8 b0 = *(const half8*)brow;
            half8 a1 = *(const half8*)(arow + 32);
            half8 b1 = *(const half8*)(brow + 32);

            f32x4 acc = {0.f, 0.f, 0.f, 0.f};
            acc = __builtin_amdgcn_mfma_f32_16x16x32_f16(a0, b0, acc, 0, 0, 0);
            acc = __builtin_amdgcn_mfma_f32_16x16x32_f16(a1, b1, acc, 0, 0, 0);

            int h0 = th * 16 + quad * 4;   // C/D: row = quad*4 + reg
            int w0 = tw * 16 + m;          //      col = lane&15
            #pragma unroll
            for (int r = 0; r < 4; ++r) {
                float v = 0.5f + acc[r];
                v = (mpf[i][r] == 0) ? 0.f : v;
                __builtin_nontemporal_store(v, &op[(h0 + r) * GRID_N + w0]);
            }
        }
    }
}

extern "C" void kernel_launch(void* const* d_in, const int* in_sizes, int n_in,
                              void* d_out, int out_size, void* d_ws, size_t ws_size,
                              hipStream_t stream) {
    const float* xL        = (const float*)d_in[0];
    const float* yL        = (const float*)d_in[1];
    const float* obj_list  = (const float*)d_in[2];
    const int*   obj_num   = (const int*)d_in[3];
    const int*   road_mask = (const int*)d_in[4];
    float*       out       = (float*)d_out;
    const int B = in_sizes[0];  // 2048

    goalmap_kernel<<<B, NT, 0, stream>>>(xL, yL, obj_list, obj_num, road_mask, out);
}